// Round 12
// baseline (291.666 us; speedup 1.0000x reference)
//
#include <hip/hip_runtime.h>
#include <math.h>

#define TAU_F 32.0f

typedef __attribute__((ext_vector_type(8))) _Float16 half8;
typedef __attribute__((ext_vector_type(2))) __fp16 half2v;
typedef __attribute__((ext_vector_type(4))) float f32x4;

union HU { uint4 u; half8 v; };

__device__ __forceinline__ void sync_lds_only() {
    // CK-style block_sync_lds: drain LDS ops, leave VMEM (vmcnt) in flight.
    asm volatile("s_waitcnt lgkmcnt(0)" ::: "memory");
    __builtin_amdgcn_s_barrier();
}

// ============ Kernel 1: FUSED G-projection + f16 hi/lo split -> gB direct ============
// Replaces gproj2+split_g3: no P roundtrip, one launch less. 256 blocks =
// mat(2) x 128 col-slices of 16, 256 thr. Each block: rows 0..95 of its mat half
// (rows 90..95 zero), cols c0..c0+16, full e=0..767 contraction in fp32 registers.
// gB layout (halves), identical to old split_g3:
//   addr = ((kc*12 + nq*3 + j)*2 + plane)*512 + lq*128 + lm*8 + (k&7)
__global__ __launch_bounds__(256) void gsplit(
    const float* __restrict__ Wt, const float* __restrict__ Wd,
    const float* __restrict__ mem, const int* __restrict__ cat,
    unsigned short* __restrict__ gB)
{
    __shared__ float Ml[96][36];   // mem rows x e-chunk (36: 16B-aligned rows, low conflict)
    __shared__ float Wl[32][20];   // e-chunk x 16 cols (20: 16B-aligned rows)

    const int bid = blockIdx.x;
    const int mat = bid >> 7;            // 0 topic (Wt), 1 domain (Wd)
    const int c0  = (bid & 127) * 16;
    const int tid = threadIdx.x;
    const float* __restrict__ W = mat ? Wd : Wt;

    const int tr = tid >> 4;             // 0..15 -> rows tr*6 .. tr*6+5
    const int tc = tid & 15;             // col c0 + tc

    float acc[6] = {0.f, 0.f, 0.f, 0.f, 0.f, 0.f};

    for (int ec = 0; ec < 24; ++ec) {
        __syncthreads();
        // stage Ml[96][32] (e-slice ec*32): 768 float4 over 256 thr x 3
        #pragma unroll
        for (int p = 0; p < 3; ++p) {
            const int u = tid + 256 * p;      // 0..767
            const int r = u >> 3, q = u & 7;
            float4 v = make_float4(0.f, 0.f, 0.f, 0.f);
            if (r < 90) {
                const int d = r / 10;
                const int mrow = cat[d] * 10 + (r - d * 10);
                v = *(const float4*)(mem + (size_t)mrow * 768 + ec * 32 + q * 4);
            }
            *(float4*)(&Ml[r][q * 4]) = v;
        }
        // stage Wl[32][16]: 512 floats = 128 float4 (threads 0..127)
        if (tid < 128) {
            const int e = tid >> 2, c4 = (tid & 3) * 4;
            *(float4*)(&Wl[e][c4]) = *(const float4*)(W + (size_t)(ec * 32 + e) * 2048 + c0 + c4);
        }
        __syncthreads();

        #pragma unroll
        for (int e = 0; e < 32; e += 4) {
            float4 m4[6];
            float w1[4];
            #pragma unroll
            for (int j = 0; j < 6; ++j) m4[j] = *(const float4*)(&Ml[tr * 6 + j][e]);
            #pragma unroll
            for (int q = 0; q < 4; ++q) w1[q] = Wl[e + q][tc];
            #pragma unroll
            for (int j = 0; j < 6; ++j) {
                acc[j] = fmaf(m4[j].x, w1[0], acc[j]);
                acc[j] = fmaf(m4[j].y, w1[1], acc[j]);
                acc[j] = fmaf(m4[j].z, w1[2], acc[j]);
                acc[j] = fmaf(m4[j].w, w1[3], acc[j]);
            }
        }
    }

    // epilogue: RNE f16 hi + residual lo, scatter to fragment layout (2B stores)
    const int k  = c0 + tc;
    const int kc = k >> 5, lq = (k >> 3) & 3, km = k & 7;
    #pragma unroll
    for (int j = 0; j < 6; ++j) {
        const int n  = mat * 96 + tr * 6 + j;
        const int nq = n / 48;
        const int rm = n - nq * 48;
        const int jj = rm >> 4, lm = rm & 15;
        const size_t base = (size_t)(kc * 12 + nq * 3 + jj) * 1024 + lq * 128 + lm * 8 + km;
        const float s = acc[j];
        const _Float16 h = (_Float16)s;                  // RNE (same as split_g3)
        const _Float16 l = (_Float16)(s - (float)h);
        gB[base]       = *(const unsigned short*)&h;     // hi plane
        gB[base + 512] = *(const unsigned short*)&l;     // lo plane
    }
}

// ============ Kernel 2: full-K split-f16 MFMA GEMM + fused softmax epilogue ============
// EXACT revert to the Round-2 verified kernel (best measured: total 242.97 us).
// 512 blocks = row-tiles of 32, full K=2048 per block.
// 256 thr = 4 waves; role nq=(w+bid)&3: nq<2 topic cols (3-pass), nq>=2 domain (1-pass).
// Main-loop barriers are lgkmcnt-only; global prefetch (A) rides through; B is L2-resident.
__global__ __launch_bounds__(256, 2) void fused_ep(
    const float* __restrict__ feat, const unsigned short* __restrict__ gB,
    float* __restrict__ out)
{
    // LDS: A-staging (split-f16, double-buffered) then REUSED as the 32x192 score panel.
    // aS: [buf2][plane2][kf2][row32][40]  (40-half rows: 16B-aligned b128, 2-way banks = free)
    // sc: [row32][193]                    (193-word stride: conflict-free per-row epilogue reads)
    __shared__ __align__(16) unsigned char smraw[32 * 193 * 4];
    unsigned short* aS = (unsigned short*)smraw;
    float* sc = (float*)smraw;
    __shared__ float ssqS[32];

    const int tid  = threadIdx.x;
    const int row0 = blockIdx.x * 32;

    const int w  = tid >> 6, l = tid & 63;
    const int lm = l & 15,  lq = l >> 4;
    const int nq = (w + blockIdx.x) & 3;     // role rotation balances SIMDs across blocks
    const bool topic = (nq < 2);
    const int sr = tid >> 3, kq = tid & 7;   // staging: row 0..31, k-octet 0..7 (64 K / step)
    const int skf = kq >> 2, sk4 = kq & 3;

    f32x4 acc[2][3];
    #pragma unroll
    for (int i = 0; i < 2; ++i)
        #pragma unroll
        for (int j = 0; j < 3; ++j) acc[i][j] = (f32x4)0.f;
    float ssq = 0.f;

    const float* fbase = feat + (size_t)(row0 + sr) * 2048 + kq * 8;
    const unsigned short* bbase = gB + nq * 3072 + l * 8;

    // convert+stage helper (fp32 -> f16 hi/lo planes, fused ssq)
    auto cw = [&](int buf, float4 va, float4 vb) {
        const float xs[8] = {va.x, va.y, va.z, va.w, vb.x, vb.y, vb.z, vb.w};
        union { half2v h2[4]; uint4 u4; } uh, ul;
        #pragma unroll
        for (int e = 0; e < 4; ++e) {
            const float a = xs[2 * e], b = xs[2 * e + 1];
            ssq = fmaf(a, a, ssq); ssq = fmaf(b, b, ssq);
            half2v h = __builtin_amdgcn_cvt_pkrtz(a, b);
            uh.h2[e] = h;
            ul.h2[e] = __builtin_amdgcn_cvt_pkrtz(a - (float)h[0], b - (float)h[1]);
        }
        *(uint4*)(aS + (size_t)(((buf * 2 + 0) * 2 + skf) * 32 + sr) * 40 + sk4 * 8) = uh.u4;
        *(uint4*)(aS + (size_t)(((buf * 2 + 1) * 2 + skf) * 32 + sr) * 40 + sk4 * 8) = ul.u4;
    };

    // ---- prologue: A steps 0,1 into regs; stage step 0 ----
    float4 c0a = *(const float4*)(fbase);
    float4 c0b = *(const float4*)(fbase + 4);
    float4 c1a = *(const float4*)(fbase + 64);
    float4 c1b = *(const float4*)(fbase + 68);
    cw(0, c0a, c0b);
    sync_lds_only();

    for (int kt = 0; kt < 32; ++kt) {
        // B for THIS step (gB is 1.57 MB -> L2-resident; latency hidden under cw + ds_reads)
        uint4 bh[6], bl[6];
        #pragma unroll
        for (int kf = 0; kf < 2; ++kf)
            #pragma unroll
            for (int j = 0; j < 3; ++j)
                bh[kf * 3 + j] = *(const uint4*)(bbase + (size_t)(2 * kt + kf) * 12288 + j * 1024);
        if (topic) {
            #pragma unroll
            for (int kf = 0; kf < 2; ++kf)
                #pragma unroll
                for (int j = 0; j < 3; ++j)
                    bl[kf * 3 + j] = *(const uint4*)(bbase + (size_t)(2 * kt + kf) * 12288 + j * 1024 + 512);
        }
        // A prefetch for step kt+2 (rides through the barrier; never drained)
        const int ka = (kt + 2 < 32) ? kt + 2 : 31;
        float4 cna = *(const float4*)(fbase + ka * 64);
        float4 cnb = *(const float4*)(fbase + ka * 64 + 4);

        // stage step kt+1 into the other buffer (no race with this-step reads)
        if (kt < 31) cw((kt + 1) & 1, c1a, c1b);

        // A fragments from buf kt&1
        const int cb = kt & 1;
        half8 fh[2][2], fl[2][2];
        #pragma unroll
        for (int i = 0; i < 2; ++i)
            #pragma unroll
            for (int kf = 0; kf < 2; ++kf) {
                HU t;
                t.u = *(const uint4*)(aS + (size_t)(((cb * 2 + 0) * 2 + kf) * 32 + i * 16 + lm) * 40 + lq * 8);
                fh[i][kf] = t.v;
            }
        if (topic) {
            #pragma unroll
            for (int i = 0; i < 2; ++i)
                #pragma unroll
                for (int kf = 0; kf < 2; ++kf) {
                    HU t;
                    t.u = *(const uint4*)(aS + (size_t)(((cb * 2 + 1) * 2 + kf) * 32 + i * 16 + lm) * 40 + lq * 8);
                    fl[i][kf] = t.v;
                }
        }

        if (topic) {
            #pragma unroll
            for (int j = 0; j < 3; ++j)
                #pragma unroll
                for (int kf = 0; kf < 2; ++kf) {
                    HU h8, l8; h8.u = bh[kf * 3 + j]; l8.u = bl[kf * 3 + j];
                    #pragma unroll
                    for (int i = 0; i < 2; ++i) {
                        acc[i][j] = __builtin_amdgcn_mfma_f32_16x16x32_f16(fh[i][kf], h8.v, acc[i][j], 0, 0, 0);
                        acc[i][j] = __builtin_amdgcn_mfma_f32_16x16x32_f16(fh[i][kf], l8.v, acc[i][j], 0, 0, 0);
                        acc[i][j] = __builtin_amdgcn_mfma_f32_16x16x32_f16(fl[i][kf], h8.v, acc[i][j], 0, 0, 0);
                    }
                }
        } else {
            #pragma unroll
            for (int j = 0; j < 3; ++j)
                #pragma unroll
                for (int kf = 0; kf < 2; ++kf) {
                    HU h8; h8.u = bh[kf * 3 + j];
                    #pragma unroll
                    for (int i = 0; i < 2; ++i)
                        acc[i][j] = __builtin_amdgcn_mfma_f32_16x16x32_f16(fh[i][kf], h8.v, acc[i][j], 0, 0, 0);
                }
        }

        sync_lds_only();   // lgkm drain + barrier only — vmcnt prefetch stays in flight
        c1a = cna; c1b = cnb;
    }

    // ---- scores -> LDS (overwrites aS; safe: last barrier drained all A-frag reads) ----
    #pragma unroll
    for (int i = 0; i < 2; ++i)
        #pragma unroll
        for (int j = 0; j < 3; ++j)
            #pragma unroll
            for (int r4 = 0; r4 < 4; ++r4)
                sc[(i * 16 + lq * 4 + r4) * 193 + nq * 48 + j * 16 + lm] = acc[i][j][r4];

    // ssq: 8 staging threads per row (kq 0..7) -> full-row |feat|^2
    ssq += __shfl_xor(ssq, 1, 64);
    ssq += __shfl_xor(ssq, 2, 64);
    ssq += __shfl_xor(ssq, 4, 64);
    if (kq == 0) ssqS[sr] = ssq;
    __syncthreads();

    // ---- softmax epilogue: 2 lanes per row (domains 0..4 / 5..8), wave 0 only ----
    if (tid < 64) {
        const int r  = tid >> 1, hf = tid & 1;
        const int nd = hf ? 4 : 5;
        const int d0 = hf ? 5 : 0;
        const float inv = TAU_F / fmaxf(sqrtf(ssqS[r]), 1e-12f);
        const float* scr = sc + (size_t)r * 193;
        float lg[5];
        float dmax = -1e30f;
        #pragma unroll
        for (int dd = 0; dd < 5; ++dd) {
            if (dd < nd) {
                const int d = d0 + dd;
                const float* v = scr + d * 10;          // topic cols 0..89
                const float* u = scr + 96 + d * 10;     // domain cols 96..185
                float mx = v[0];
                #pragma unroll
                for (int m = 1; m < 10; ++m) mx = fmaxf(mx, v[m]);
                float ssum = 0.f, dot = 0.f;
                #pragma unroll
                for (int m = 0; m < 10; ++m) {
                    const float p = __expf((v[m] - mx) * inv);
                    ssum += p;
                    dot = fmaf(p, u[m], dot);
                }
                const float lgt = (dot / ssum) * inv;
                lg[dd] = lgt;
                dmax = fmaxf(dmax, lgt);
            } else {
                lg[dd] = -1e30f;                        // exp -> 0, doesn't affect sums
            }
        }
        dmax = fmaxf(dmax, __shfl_xor(dmax, 1, 64));
        float s2 = 0.f;
        #pragma unroll
        for (int dd = 0; dd < 5; ++dd) {
            const float p = __expf(lg[dd] - dmax);
            lg[dd] = p;
            s2 += p;
        }
        s2 += __shfl_xor(s2, 1, 64);
        const float r2 = 1.0f / s2;
        #pragma unroll
        for (int dd = 0; dd < 5; ++dd)
            if (dd < nd)
                out[(size_t)(row0 + r) * 9 + d0 + dd] = lg[dd] * r2;
    }
}

extern "C" void kernel_launch(void* const* d_in, const int* in_sizes, int n_in,
                              void* d_out, int out_size, void* d_ws, size_t ws_size,
                              hipStream_t stream) {
    const float* feature = (const float*)d_in[0];
    const float* Wt      = (const float*)d_in[1];
    const float* Wd      = (const float*)d_in[2];
    const float* mem     = (const float*)d_in[3];
    const int*   cat     = (const int*)d_in[4];

    // ws layout: gB 1.57 MB @50331648 (P eliminated by gsplit fusion)
    unsigned short* gB = (unsigned short*)((char*)d_ws + 50331648);
    float* out = (float*)d_out;

    gsplit<<<256, 256, 0, stream>>>(Wt, Wd, mem, cat, gB);
    fused_ep<<<512, 256, 0, stream>>>(feature, gB, out);
}